// Round 9
// baseline (166.417 us; speedup 1.0000x reference)
//
#include <hip/hip_runtime.h>
#include <hip/hip_bf16.h>

typedef short short8 __attribute__((ext_vector_type(8)));
typedef float f32x4 __attribute__((ext_vector_type(4)));

#define NB 4096   // batch rows
#define KZ 2048   // concat K (IN + OUT)
#define NG 1024   // per-gate output cols
#define NKS 32    // macro K-steps of 64 (each does wh and wl sharing A)

__device__ __forceinline__ unsigned short f2bf(float f) {
  unsigned int u = __float_as_uint(f);
  u += 0x7FFFu + ((u >> 16) & 1u);   // RNE
  return (unsigned short)(u >> 16);
}
__device__ __forceinline__ float bf2f(unsigned short s) {
  return __uint_as_float(((unsigned int)s) << 16);
}
__device__ __forceinline__ void gload_lds16(const void* g, void* l) {
  __builtin_amdgcn_global_load_lds(
      (__attribute__((address_space(1))) void*)g,
      (__attribute__((address_space(3))) void*)l, 16, 0, 0);
}
// direct global->VGPR 16B load of a B fragment (weights, L2-resident)
__device__ __forceinline__ short8 bload(const unsigned short* p) {
  short8 r;
  asm volatile("global_load_dwordx4 %0, %1, off" : "=v"(r) : "v"(p));
  return r;
}
__device__ __forceinline__ float sigm(float x) { return 1.f / (1.f + __expf(-x)); }
__device__ __forceinline__ float tanh_fast(float x) {
  float e = __expf(-2.f * fabsf(x));
  float r = (1.f - e) / (1.f + e);
  return copysignf(r, x);
}

// ---- concat([x,h]) -> bf16 zh [4096][2048] ----
__global__ void zsplit_kernel(const float* __restrict__ x, const float* __restrict__ h,
                              unsigned short* __restrict__ zh) {
  int idx = blockIdx.x * 256 + threadIdx.x;
  int e = idx << 2;
  int r = e >> 11;
  int k = e & (KZ - 1);
  const float* src = (k < 1024) ? (x + ((size_t)r << 10) + k)
                                : (h + ((size_t)r << 10) + (k - 1024));
  float4 v = *reinterpret_cast<const float4*>(src);
  float vf[4] = {v.x, v.y, v.z, v.w};
  unsigned short hh[4];
#pragma unroll
  for (int j = 0; j < 4; ++j) hh[j] = f2bf(vf[j]);
  uint2 H = make_uint2((unsigned)hh[0] | ((unsigned)hh[1] << 16),
                       (unsigned)hh[2] | ((unsigned)hh[3] << 16));
  *reinterpret_cast<uint2*>(zh + e) = H;
}

// ---- transpose + hi/lo split weights into gate-interleaved packed rows ----
// p = (n>>6)<<8 | ((n>>4)&3)<<6 | g<<4 | (n&15)
__global__ void wsplit_kernel(const float* __restrict__ w0, const float* __restrict__ w1,
                              const float* __restrict__ w2, const float* __restrict__ w3,
                              unsigned short* __restrict__ wh, unsigned short* __restrict__ wl) {
  __shared__ float tile[32][33];
  int g = blockIdx.z;
  const float* w = (g == 0) ? w0 : (g == 1) ? w1 : (g == 2) ? w2 : w3;
  int k0 = blockIdx.x << 5;
  int n0 = blockIdx.y << 5;
  int t = threadIdx.x;
  int rk = t >> 3, q = t & 7;
  float4 v = *reinterpret_cast<const float4*>(w + (size_t)(k0 + rk) * NG + n0 + (q << 2));
  tile[rk][(q << 2) + 0] = v.x;
  tile[rk][(q << 2) + 1] = v.y;
  tile[rk][(q << 2) + 2] = v.z;
  tile[rk][(q << 2) + 3] = v.w;
  __syncthreads();
  int n = t >> 3, kq = t & 7;
  unsigned short hs[4], ls[4];
#pragma unroll
  for (int j = 0; j < 4; ++j) {
    float f = tile[(kq << 2) + j][n];
    unsigned short hi = f2bf(f);
    unsigned short lo = f2bf(f - bf2f(hi));
    hs[j] = hi; ls[j] = lo;
  }
  int nn = n0 + n;
  int p = ((nn >> 6) << 8) | (((nn >> 4) & 3) << 6) | (g << 4) | (nn & 15);
  size_t o = (size_t)p * KZ + k0 + (kq << 2);
  uint2 H = make_uint2((unsigned)hs[0] | ((unsigned)hs[1] << 16),
                       (unsigned)hs[2] | ((unsigned)hs[3] << 16));
  uint2 L = make_uint2((unsigned)ls[0] | ((unsigned)ls[1] << 16),
                       (unsigned)ls[2] | ((unsigned)ls[3] << 16));
  *reinterpret_cast<uint2*>(wh + o) = H;
  *reinterpret_cast<uint2*>(wl + o) = L;
}

#define MFMA(a, b, c) __builtin_amdgcn_mfma_f32_16x16x32_bf16((a), (b), (c), 0, 0, 0)
#define BAR() __builtin_amdgcn_s_barrier()
#define LGKM0() asm volatile("s_waitcnt lgkmcnt(0)" ::: "memory")
#define VMC0() asm volatile("s_waitcnt vmcnt(0)" ::: "memory")
#define VMC4() asm volatile("s_waitcnt vmcnt(4)" ::: "memory")
#define VMC8() asm volatile("s_waitcnt vmcnt(8)" ::: "memory")
#define SB() __builtin_amdgcn_sched_barrier(0)
#define PRIO1() __builtin_amdgcn_s_setprio(1)
#define PRIO0() __builtin_amdgcn_s_setprio(0)

// ---- 256x256 fused 4-gate GEMM + LSTM epilogue ----
// A (activations) through LDS double-buffer; B (weights) streamed L2->VGPR
// with quarter-granularity prefetch and counted vmcnt. 1 barrier/macro.
// Quarters: Q1 = a(k0) x bh(k0); Q2 = a(k0) x bl(k0); Q3 = a(k1) x bh(k1); Q4 = a(k1) x bl(k1).
__global__ __launch_bounds__(512, 2) void lstm_gemm256_kernel(
    const unsigned short* __restrict__ zh,
    const unsigned short* __restrict__ wh, const unsigned short* __restrict__ wl,
    const float* __restrict__ c_in, const float* __restrict__ bf_,
    const float* __restrict__ bi_, const float* __restrict__ bc_,
    const float* __restrict__ bo_, float* __restrict__ out) {
  __shared__ unsigned short As[2 * 16384];   // 2 dbuf x 256 rows x 64 k = 64 KB (A only)
  const int t = threadIdx.x;
  const int lane = t & 63;
  const int wid = t >> 6;
  const int wr = wid >> 2;          // 0..1 M half
  const int wc = wid & 3;           // 0..3 N quarter (64 packed cols)
  const int l15 = lane & 15;
  const int l4 = lane >> 4;

  // XCD swizzle for B L2-residency: each XCD owns 2 weight col-panels (4MB ~= L2)
  const int bid = blockIdx.x;
  const int xcd = bid & 7;
  const int i = bid >> 3;
  const int bx = (xcd << 1) | (i & 1);   // 0..15 col-block (256 packed cols)
  const int by = i >> 1;                 // 0..15 row-block
  const int brow0 = by << 8;
  const int pcol0 = bx << 8;

  char* AsB = (char*)As;

  // A staging: LDS linear dest, XOR slot-swizzled global source (4 gload_lds / thread)
  int aoff[4];
#pragma unroll
  for (int j = 0; j < 4; ++j) {
    int row = (j << 6) + (t >> 3);
    int sl = (t & 7) ^ (row & 7);
    aoff[j] = (brow0 + row) * KZ + (sl << 3);
  }
  const int ldsw = wid << 10;

  auto STAGEA = [&](int s) {               // caller guarantees s < NKS
    const int kk = s << 6;
    const int lb = (s & 1) << 15;
#pragma unroll
    for (int j = 0; j < 4; ++j)
      gload_lds16(zh + aoff[j] + kk, AsB + lb + (j << 13) + ldsw);
  };

  f32x4 acc[8][4];
#pragma unroll
  for (int m = 0; m < 8; ++m)
#pragma unroll
    for (int n = 0; n < 4; ++n) acc[m][n] = (f32x4){0.f, 0.f, 0.f, 0.f};

  // LDS read constants (A)
  const int rx = l15 & 7;
  const int sx0 = (l4 ^ rx) << 4;          // k-slot 0
  const int sx1 = ((4 + l4) ^ rx) << 4;    // k-slot 1
  const int aB = l15 << 7;
  const int aW = wr << 14;

  // B address constants: fragment nf(gate): row = pcol0 + wc*64 + nf*16 + l15
  int rowoff[4];
#pragma unroll
  for (int nf = 0; nf < 4; ++nf)
    rowoff[nf] = (pcol0 + (wc << 6) + (nf << 4) + l15) * KZ;
  const int kb = l4 << 3;                  // lane k-chunk (8 elems)

  short8 a[8], bh0[4], bl0[4], bh1[4], bl1[4];

  // prologue: A(0)->buf0, A(1)->buf1, B(m=0, bh,k0); drain; barrier
  STAGEA(0); STAGEA(1);
#pragma unroll
  for (int nf = 0; nf < 4; ++nf) bh0[nf] = bload(wh + rowoff[nf] + kb);
  VMC0();
  BAR();

  for (int m = 0; m < NKS; ++m) {
    const int abase = ((m & 1) << 15) + aW;
    const int kel = m << 6;

    // ---- Q1: ds_read a(k0); load bl(k0); wait bh(k0); MFMA a x bh0 ----
#pragma unroll
    for (int mm = 0; mm < 8; ++mm)
      a[mm] = *reinterpret_cast<const short8*>(AsB + abase + aB + (mm << 11) + sx0);
#pragma unroll
    for (int nf = 0; nf < 4; ++nf) bl0[nf] = bload(wl + rowoff[nf] + kel + kb);
    if (m < NKS - 1) { VMC8(); } else { VMC4(); }
    SB();
    LGKM0(); SB();
    PRIO1();
#pragma unroll
    for (int mm = 0; mm < 8; ++mm)
#pragma unroll
      for (int nf = 0; nf < 4; ++nf) acc[mm][nf] = MFMA(a[mm], bh0[nf], acc[mm][nf]);
    PRIO0();

    // ---- Q2: load bh(k1); wait bl(k0) (also retires A-stage); MFMA a x bl0 ----
#pragma unroll
    for (int nf = 0; nf < 4; ++nf) bh1[nf] = bload(wh + rowoff[nf] + kel + 32 + kb);
    VMC4(); SB();
    PRIO1();
#pragma unroll
    for (int mm = 0; mm < 8; ++mm)
#pragma unroll
      for (int nf = 0; nf < 4; ++nf) acc[mm][nf] = MFMA(a[mm], bl0[nf], acc[mm][nf]);
    PRIO0();

    // ---- Q3: ds_read a(k1); load bl(k1); wait bh(k1); MFMA a x bh1 ----
#pragma unroll
    for (int mm = 0; mm < 8; ++mm)
      a[mm] = *reinterpret_cast<const short8*>(AsB + abase + aB + (mm << 11) + sx1);
#pragma unroll
    for (int nf = 0; nf < 4; ++nf) bl1[nf] = bload(wl + rowoff[nf] + kel + 32 + kb);
    VMC4(); SB();
    LGKM0(); SB();
    PRIO1();
#pragma unroll
    for (int mm = 0; mm < 8; ++mm)
#pragma unroll
      for (int nf = 0; nf < 4; ++nf) acc[mm][nf] = MFMA(a[mm], bh1[nf], acc[mm][nf]);
    PRIO0();

    // ---- Q4: barrier (A WAR); load bh(k0, m+1); stage A(m+2); wait bl(k1); MFMA ----
    BAR();
    if (m < NKS - 1) {
#pragma unroll
      for (int nf = 0; nf < 4; ++nf) bh0[nf] = bload(wh + rowoff[nf] + kel + 64 + kb);
    }
    if (m < NKS - 2) STAGEA(m + 2);
    if (m < NKS - 2)      { VMC8(); }
    else if (m < NKS - 1) { VMC4(); }
    else                  { VMC0(); }
    SB();
    PRIO1();
#pragma unroll
    for (int mm = 0; mm < 8; ++mm)
#pragma unroll
      for (int nf = 0; nf < 4; ++nf) acc[mm][nf] = MFMA(a[mm], bl1[nf], acc[mm][nf]);
    PRIO0();
  }

  // ---- epilogue: lane holds all 4 gates (col-frags) for one column ----
  const int ng = (bx << 6) + (wc << 4) + l15;
  const float vbf = bf_[ng], vbi = bi_[ng], vbc = bc_[ng], vbo = bo_[ng];
#pragma unroll
  for (int m = 0; m < 8; ++m) {
#pragma unroll
    for (int r = 0; r < 4; ++r) {
      const int row = brow0 + (wr << 7) + (m << 4) + (l4 << 2) + r;
      const float fp = acc[m][0][r] + vbf;
      const float ip = acc[m][1][r] + vbi;
      const float gp = acc[m][2][r] + vbc;
      const float op = acc[m][3][r] + vbo;
      const float co = c_in[(size_t)row * NG + ng];
      const float cnew = co * sigm(fp) + sigm(ip) * tanh_fast(gp);
      out[(size_t)row * NG + ng] = tanh_fast(cnew) * sigm(op);
    }
  }
}

extern "C" void kernel_launch(void* const* d_in, const int* in_sizes, int n_in,
                              void* d_out, int out_size, void* d_ws, size_t ws_size,
                              hipStream_t stream) {
  const float* x   = (const float*)d_in[0];
  const float* h   = (const float*)d_in[1];
  const float* c   = (const float*)d_in[2];
  const float* w_f = (const float*)d_in[3];
  const float* b_f = (const float*)d_in[4];
  const float* w_i = (const float*)d_in[5];
  const float* b_i = (const float*)d_in[6];
  const float* w_c = (const float*)d_in[7];
  const float* b_c = (const float*)d_in[8];
  const float* w_o = (const float*)d_in[9];
  const float* b_o = (const float*)d_in[10];
  float* out = (float*)d_out;

  unsigned short* zh = (unsigned short*)d_ws;                 // 16 MB
  unsigned short* wh = zh + (size_t)NB * KZ;                  // 16 MB
  unsigned short* wl = wh + (size_t)KZ * 4096;                // 16 MB

  zsplit_kernel<<<(NB * KZ / 4) / 256, 256, 0, stream>>>(x, h, zh);
  wsplit_kernel<<<dim3(KZ / 32, NG / 32, 4), 256, 0, stream>>>(w_f, w_i, w_c, w_o, wh, wl);
  lstm_gemm256_kernel<<<256, 512, 0, stream>>>(zh, wh, wl, c,
                                               b_f, b_i, b_c, b_o, out);
}

// Round 10
// 158.825 us; speedup vs baseline: 1.0478x; 1.0478x over previous
//
#include <hip/hip_runtime.h>
#include <hip/hip_bf16.h>

typedef short short8 __attribute__((ext_vector_type(8)));
typedef float f32x16 __attribute__((ext_vector_type(16)));

#define NB 4096   // batch rows
#define KZ 2048   // concat K (IN + OUT)
#define NG 1024   // per-gate output cols
#define NKS 32    // macro K-steps of 64 (each does wh and wl sharing A)

__device__ __forceinline__ unsigned short f2bf(float f) {
  unsigned int u = __float_as_uint(f);
  u += 0x7FFFu + ((u >> 16) & 1u);   // RNE
  return (unsigned short)(u >> 16);
}
__device__ __forceinline__ float bf2f(unsigned short s) {
  return __uint_as_float(((unsigned int)s) << 16);
}
__device__ __forceinline__ void gload_lds16(const void* g, void* l) {
  __builtin_amdgcn_global_load_lds(
      (__attribute__((address_space(1))) void*)g,
      (__attribute__((address_space(3))) void*)l, 16, 0, 0);
}
__device__ __forceinline__ float sigm(float x) { return 1.f / (1.f + __expf(-x)); }
__device__ __forceinline__ float tanh_fast(float x) {
  float e = __expf(-2.f * fabsf(x));
  float r = (1.f - e) / (1.f + e);
  return copysignf(r, x);
}

// ---- concat([x,h]) -> bf16 zh [4096][2048] ----
__global__ void zsplit_kernel(const float* __restrict__ x, const float* __restrict__ h,
                              unsigned short* __restrict__ zh) {
  int idx = blockIdx.x * 256 + threadIdx.x;
  int e = idx << 2;
  int r = e >> 11;
  int k = e & (KZ - 1);
  const float* src = (k < 1024) ? (x + ((size_t)r << 10) + k)
                                : (h + ((size_t)r << 10) + (k - 1024));
  float4 v = *reinterpret_cast<const float4*>(src);
  float vf[4] = {v.x, v.y, v.z, v.w};
  unsigned short hh[4];
#pragma unroll
  for (int j = 0; j < 4; ++j) hh[j] = f2bf(vf[j]);
  uint2 H = make_uint2((unsigned)hh[0] | ((unsigned)hh[1] << 16),
                       (unsigned)hh[2] | ((unsigned)hh[3] << 16));
  *reinterpret_cast<uint2*>(zh + e) = H;
}

// ---- transpose + hi/lo split weights into gate-paired packed rows ----
// p = (n>>6)<<8 | ((n>>4)&3)<<6 | (g>>1)<<5 | (g&1)<<4 | (n&15)
// => per wave (64 packed): tile0 (32) = gates {f,i}, tile1 = {c,o}; 32x32 col = packed.
__global__ void wsplit_kernel(const float* __restrict__ w0, const float* __restrict__ w1,
                              const float* __restrict__ w2, const float* __restrict__ w3,
                              unsigned short* __restrict__ wh, unsigned short* __restrict__ wl) {
  __shared__ float tile[32][33];
  int g = blockIdx.z;
  const float* w = (g == 0) ? w0 : (g == 1) ? w1 : (g == 2) ? w2 : w3;
  int k0 = blockIdx.x << 5;
  int n0 = blockIdx.y << 5;
  int t = threadIdx.x;
  int rk = t >> 3, q = t & 7;
  float4 v = *reinterpret_cast<const float4*>(w + (size_t)(k0 + rk) * NG + n0 + (q << 2));
  tile[rk][(q << 2) + 0] = v.x;
  tile[rk][(q << 2) + 1] = v.y;
  tile[rk][(q << 2) + 2] = v.z;
  tile[rk][(q << 2) + 3] = v.w;
  __syncthreads();
  int n = t >> 3, kq = t & 7;
  unsigned short hs[4], ls[4];
#pragma unroll
  for (int j = 0; j < 4; ++j) {
    float f = tile[(kq << 2) + j][n];
    unsigned short hi = f2bf(f);
    unsigned short lo = f2bf(f - bf2f(hi));
    hs[j] = hi; ls[j] = lo;
  }
  int nn = n0 + n;
  int p = ((nn >> 6) << 8) | (((nn >> 4) & 3) << 6) | ((g >> 1) << 5) | ((g & 1) << 4) | (nn & 15);
  size_t o = (size_t)p * KZ + k0 + (kq << 2);
  uint2 H = make_uint2((unsigned)hs[0] | ((unsigned)hs[1] << 16),
                       (unsigned)hs[2] | ((unsigned)hs[3] << 16));
  uint2 L = make_uint2((unsigned)ls[0] | ((unsigned)ls[1] << 16),
                       (unsigned)ls[2] | ((unsigned)ls[3] << 16));
  *reinterpret_cast<uint2*>(wh + o) = H;
  *reinterpret_cast<uint2*>(wl + o) = L;
}

#define MFMA32(a, b, c) __builtin_amdgcn_mfma_f32_32x32x16_bf16((a), (b), (c), 0, 0, 0)
#define BAR() __builtin_amdgcn_s_barrier()
#define LGKM(N) asm volatile("s_waitcnt lgkmcnt(" #N ")" ::: "memory")
#define VMC0() asm volatile("s_waitcnt vmcnt(0)" ::: "memory")
#define SB() __builtin_amdgcn_sched_barrier(0)
#define PRIO1() __builtin_amdgcn_s_setprio(1)
#define PRIO0() __builtin_amdgcn_s_setprio(0)

// ---- 256x256 fused 4-gate GEMM (32x32x16 MFMA) + LSTM epilogue ----
// 8 waves (2M x 4N); per-wave 128 rows x 64 packed cols (2 N-tiles of 32).
// K-loop: 32 macros of K=64 (4 kslots of 16), A shared across wh & wl.
__global__ __launch_bounds__(512, 2) void lstm_gemm256_kernel(
    const unsigned short* __restrict__ zh,
    const unsigned short* __restrict__ wh, const unsigned short* __restrict__ wl,
    const float* __restrict__ c_in, const float* __restrict__ bf_,
    const float* __restrict__ bi_, const float* __restrict__ bc_,
    const float* __restrict__ bo_, float* __restrict__ out) {
  __shared__ unsigned short As[2 * 16384];   // 2 dbuf x 256 rows x 64 k = 64 KB
  __shared__ unsigned short Bh[16384];       // wh tile, 32 KB
  __shared__ unsigned short Bl[16384];       // wl tile, 32 KB
  const int t = threadIdx.x;
  const int lane = t & 63;
  const int wid = t >> 6;
  const int wr = wid >> 2;          // 0..1 M half
  const int wc = wid & 3;           // 0..3 N quarter (64 packed cols)
  const int l31 = lane & 31;
  const int l5 = lane >> 5;

  // XCD column-pinning swizzle: each XCD owns 2 col-panels (weights L2-resident)
  const int bid = blockIdx.x;
  const int xcd = bid & 7;
  const int i = bid >> 3;
  const int bx = (xcd << 1) | (i & 1);
  const int by = i >> 1;
  const int brow0 = by << 8;
  const int pcol0 = bx << 8;

  char* AsB = (char*)As;
  char* BhB = (char*)Bh;
  char* BlB = (char*)Bl;

  // stage addressing: LDS linear dest, XOR slot-swizzled global source
  int aoff[2], boff[2];
#pragma unroll
  for (int j = 0; j < 2; ++j) {
    int row = (j << 6) + (t >> 3);
    int sl = (t & 7) ^ (row & 7);
    aoff[j] = (brow0 + row) * KZ + (sl << 3);
    boff[j] = (pcol0 + row) * KZ + (sl << 3);
  }
  const int ldsw = wid << 10;

  // hx: 0,1 = A halves (dbuf by s&1); 2,3 = Bh halves; 4,5 = Bl halves
  auto STAGE = [&](int s, int hx) {
    if (s >= NKS) return;
    const int kk = s << 6;
    if (hx < 2) {
      const int lb = ((s & 1) << 15) + (hx << 14);
#pragma unroll
      for (int j = 0; j < 2; ++j)
        gload_lds16(zh + aoff[j] + hx * (128 * KZ) + kk, AsB + lb + (j << 13) + ldsw);
    } else if (hx < 4) {
      const int hq = hx - 2;
#pragma unroll
      for (int j = 0; j < 2; ++j)
        gload_lds16(wh + boff[j] + hq * (128 * KZ) + kk, BhB + (hq << 14) + (j << 13) + ldsw);
    } else {
      const int hq = hx - 4;
#pragma unroll
      for (int j = 0; j < 2; ++j)
        gload_lds16(wl + boff[j] + hq * (128 * KZ) + kk, BlB + (hq << 14) + (j << 13) + ldsw);
    }
  };

  f32x16 acc[4][2];
#pragma unroll
  for (int mt = 0; mt < 4; ++mt)
#pragma unroll
    for (int nt = 0; nt < 2; ++nt)
#pragma unroll
      for (int r = 0; r < 16; ++r) acc[mt][nt][r] = 0.f;

  // per-lane read constants: frag = 8 contiguous bf16 at (row = l31, k = ks*16 + l5*8)
  const int rx = lane & 7;
  int sxk[4];
#pragma unroll
  for (int ks = 0; ks < 4; ++ks) sxk[ks] = (((ks << 1) + l5) ^ rx) << 4;
  const int aR = l31 << 7;              // row byte offset within tile
  const int aW = wr << 14;              // wave A base (128 rows)
  const int bWq = wc << 13;             // wave B base (64 packed rows)

  short8 aF0[4], aF1[4], bh0F[2], bh1F[2], bl0F[2], bl1F[2];

  // prologue: A(0)->buf0, Bh(0), Bl(0); drain; barrier
  STAGE(0, 0); STAGE(0, 1); STAGE(0, 2); STAGE(0, 3); STAGE(0, 4); STAGE(0, 5);
  VMC0();
  BAR();

  for (int m = 0; m < NKS; ++m) {
    const int abase = ((m & 1) << 15) + aW;

    auto RD = [&](short8* aF, short8* bhF, short8* blF, int sx) {
#pragma unroll
      for (int mt = 0; mt < 4; ++mt)
        aF[mt] = *reinterpret_cast<const short8*>(AsB + abase + (mt << 12) + aR + sx);
#pragma unroll
      for (int nt = 0; nt < 2; ++nt) {
        bhF[nt] = *reinterpret_cast<const short8*>(BhB + bWq + (nt << 12) + aR + sx);
        blF[nt] = *reinterpret_cast<const short8*>(BlB + bWq + (nt << 12) + aR + sx);
      }
    };
    auto MM = [&](const short8* aF, const short8* bF) {
#pragma unroll
      for (int mt = 0; mt < 4; ++mt)
#pragma unroll
        for (int nt = 0; nt < 2; ++nt)
          acc[mt][nt] = MFMA32(aF[mt], bF[nt], acc[mt][nt]);
    };

    // stage A(m+1) early (dbuf; WAR-safe: A(m-1) reads retired last macro)
    STAGE(m + 1, 0); STAGE(m + 1, 1);

    RD(aF0, bh0F, bl0F, sxk[0]);                 // group 0 (ks0)
    SB();
    RD(aF1, bh1F, bl1F, sxk[1]);                 // group 1 (ks1)
    SB();
    LGKM(8); SB();                               // ks0 ready
    PRIO1(); MM(aF0, bh0F); MM(aF0, bl0F); PRIO0();

    RD(aF0, bh0F, bl0F, sxk[2]);                 // group 2 (ks2)
    SB();
    LGKM(8); SB();                               // ks1 ready
    PRIO1(); MM(aF1, bh1F); MM(aF1, bl1F); PRIO0();

    RD(aF1, bh1F, bl1F, sxk[3]);                 // group 3 (ks3)
    SB();
    LGKM(8); SB();                               // ks2 ready
    PRIO1(); MM(aF0, bh0F); MM(aF0, bl0F); PRIO0();

    LGKM(0); SB();                               // ks3 retired (WAR-ready)
    BAR();                                       // all waves' A(m)/B(m) reads retired
    STAGE(m + 1, 2); STAGE(m + 1, 3);            // Bh(m+1)
    STAGE(m + 1, 4); STAGE(m + 1, 5);            // Bl(m+1)
    PRIO1(); MM(aF1, bh1F); MM(aF1, bl1F); PRIO0();
    VMC0(); SB();                                // all stages landed (A' old, B' ~1 group)
    BAR();
  }

  // ---- epilogue: gate pair exchange via shfl_xor(16), then LSTM math ----
  // lane holds gates (gh, gh+2)? -> tile0 = {f,i}, tile1 = {c,o}; partner lane^16.
  const int c = lane & 15;
  const int gh = (lane >> 4) & 1;
  const int ng = (bx << 6) + (wc << 4) + c;
  const float vbf = bf_[ng], vbi = bi_[ng], vbc = bc_[ng], vbo = bo_[ng];
#pragma unroll
  for (int mt = 0; mt < 4; ++mt) {
    float oth0[16], oth1[16];
#pragma unroll
    for (int r = 0; r < 16; ++r) {
      oth0[r] = __shfl_xor(acc[mt][0][r], 16, 64);
      oth1[r] = __shfl_xor(acc[mt][1][r], 16, 64);
    }
#pragma unroll
    for (int r = 0; r < 16; ++r) {
      const int row = brow0 + (wr << 7) + (mt << 5) + (r & 3) + ((r >> 2) << 3) + (l5 << 2);
      const float fp = (gh ? oth0[r] : acc[mt][0][r]) + vbf;
      const float ip = (gh ? acc[mt][0][r] : oth0[r]) + vbi;
      const float gp = (gh ? oth1[r] : acc[mt][1][r]) + vbc;
      const float op = (gh ? acc[mt][1][r] : oth1[r]) + vbo;
      const float co = c_in[(size_t)row * NG + ng];
      const float cnew = co * sigm(fp) + sigm(ip) * tanh_fast(gp);
      out[(size_t)row * NG + ng] = tanh_fast(cnew) * sigm(op);
    }
  }
}

extern "C" void kernel_launch(void* const* d_in, const int* in_sizes, int n_in,
                              void* d_out, int out_size, void* d_ws, size_t ws_size,
                              hipStream_t stream) {
  const float* x   = (const float*)d_in[0];
  const float* h   = (const float*)d_in[1];
  const float* c   = (const float*)d_in[2];
  const float* w_f = (const float*)d_in[3];
  const float* b_f = (const float*)d_in[4];
  const float* w_i = (const float*)d_in[5];
  const float* b_i = (const float*)d_in[6];
  const float* w_c = (const float*)d_in[7];
  const float* b_c = (const float*)d_in[8];
  const float* w_o = (const float*)d_in[9];
  const float* b_o = (const float*)d_in[10];
  float* out = (float*)d_out;

  unsigned short* zh = (unsigned short*)d_ws;                 // 16 MB
  unsigned short* wh = zh + (size_t)NB * KZ;                  // 16 MB
  unsigned short* wl = wh + (size_t)KZ * 4096;                // 16 MB

  zsplit_kernel<<<(NB * KZ / 4) / 256, 256, 0, stream>>>(x, h, zh);
  wsplit_kernel<<<dim3(KZ / 32, NG / 32, 4), 256, 0, stream>>>(w_f, w_i, w_c, w_o, wh, wl);
  lstm_gemm256_kernel<<<256, 512, 0, stream>>>(zh, wh, wl, c,
                                               b_f, b_i, b_c, b_o, out);
}

// Round 11
// 151.606 us; speedup vs baseline: 1.0977x; 1.0476x over previous
//
#include <hip/hip_runtime.h>
#include <hip/hip_bf16.h>

typedef short short8 __attribute__((ext_vector_type(8)));
typedef float f32x4 __attribute__((ext_vector_type(4)));

#define NB 4096    // batch rows
#define KZ 2048    // concat K (IN + OUT)
#define NG 1024    // per-gate output cols
#define NSTEP 64   // half-steps of K=32

__device__ __forceinline__ unsigned short f2bf(float f) {
  unsigned int u = __float_as_uint(f);
  u += 0x7FFFu + ((u >> 16) & 1u);   // RNE
  return (unsigned short)(u >> 16);
}
__device__ __forceinline__ float bf2f(unsigned short s) {
  return __uint_as_float(((unsigned int)s) << 16);
}
__device__ __forceinline__ void gload_lds16(const void* g, void* l) {
  __builtin_amdgcn_global_load_lds(
      (__attribute__((address_space(1))) void*)g,
      (__attribute__((address_space(3))) void*)l, 16, 0, 0);
}
__device__ __forceinline__ float sigm(float x) { return 1.f / (1.f + __expf(-x)); }
__device__ __forceinline__ float tanh_fast(float x) {
  float e = __expf(-2.f * fabsf(x));
  float r = (1.f - e) / (1.f + e);
  return copysignf(r, x);
}

// ---- concat([x,h]) -> bf16 zh [4096][2048] ----
__global__ void zsplit_kernel(const float* __restrict__ x, const float* __restrict__ h,
                              unsigned short* __restrict__ zh) {
  int idx = blockIdx.x * 256 + threadIdx.x;
  int e = idx << 2;
  int r = e >> 11;
  int k = e & (KZ - 1);
  const float* src = (k < 1024) ? (x + ((size_t)r << 10) + k)
                                : (h + ((size_t)r << 10) + (k - 1024));
  float4 v = *reinterpret_cast<const float4*>(src);
  float vf[4] = {v.x, v.y, v.z, v.w};
  unsigned short hh[4];
#pragma unroll
  for (int j = 0; j < 4; ++j) hh[j] = f2bf(vf[j]);
  uint2 H = make_uint2((unsigned)hh[0] | ((unsigned)hh[1] << 16),
                       (unsigned)hh[2] | ((unsigned)hh[3] << 16));
  *reinterpret_cast<uint2*>(zh + e) = H;
}

// ---- transpose + hi/lo split weights into gate-interleaved packed rows ----
// p = (n>>6)<<8 | ((n>>4)&3)<<6 | g<<4 | (n&15)   (each wave's 64 cols = 4 gates x 16)
__global__ void wsplit_kernel(const float* __restrict__ w0, const float* __restrict__ w1,
                              const float* __restrict__ w2, const float* __restrict__ w3,
                              unsigned short* __restrict__ wh, unsigned short* __restrict__ wl) {
  __shared__ float tile[32][33];
  int g = blockIdx.z;
  const float* w = (g == 0) ? w0 : (g == 1) ? w1 : (g == 2) ? w2 : w3;
  int k0 = blockIdx.x << 5;
  int n0 = blockIdx.y << 5;
  int t = threadIdx.x;
  int rk = t >> 3, q = t & 7;
  float4 v = *reinterpret_cast<const float4*>(w + (size_t)(k0 + rk) * NG + n0 + (q << 2));
  tile[rk][(q << 2) + 0] = v.x;
  tile[rk][(q << 2) + 1] = v.y;
  tile[rk][(q << 2) + 2] = v.z;
  tile[rk][(q << 2) + 3] = v.w;
  __syncthreads();
  int n = t >> 3, kq = t & 7;
  unsigned short hs[4], ls[4];
#pragma unroll
  for (int j = 0; j < 4; ++j) {
    float f = tile[(kq << 2) + j][n];
    unsigned short hi = f2bf(f);
    unsigned short lo = f2bf(f - bf2f(hi));
    hs[j] = hi; ls[j] = lo;
  }
  int nn = n0 + n;
  int p = ((nn >> 6) << 8) | (((nn >> 4) & 3) << 6) | (g << 4) | (nn & 15);
  size_t o = (size_t)p * KZ + k0 + (kq << 2);
  uint2 H = make_uint2((unsigned)hs[0] | ((unsigned)hs[1] << 16),
                       (unsigned)hs[2] | ((unsigned)hs[3] << 16));
  uint2 L = make_uint2((unsigned)ls[0] | ((unsigned)ls[1] << 16),
                       (unsigned)ls[2] | ((unsigned)ls[3] << 16));
  *reinterpret_cast<uint2*>(wh + o) = H;
  *reinterpret_cast<uint2*>(wl + o) = L;
}

#define MFMA(a, b, c) __builtin_amdgcn_mfma_f32_16x16x32_bf16((a), (b), (c), 0, 0, 0)
#define BAR() __builtin_amdgcn_s_barrier()
#define LGKM(N) asm volatile("s_waitcnt lgkmcnt(" #N ")" ::: "memory")
#define VMC(N) asm volatile("s_waitcnt vmcnt(" #N ")" ::: "memory")
#define SB() __builtin_amdgcn_sched_barrier(0)
#define PRIO1() __builtin_amdgcn_s_setprio(1)
#define PRIO0() __builtin_amdgcn_s_setprio(0)

// ---- 128x256 fused 4-gate GEMM + LSTM epilogue, fully multi-buffered ----
// 8 waves (2M x 4N), wave = 64 rows x 64 packed cols; half-steps of K=32.
// A: 2-buf (per-macro); Bh/Bl: 3-buf (per-step, stage 2 ahead). Counted waits only.
__global__ __launch_bounds__(512, 2) void lstm_gemm_kernel(
    const unsigned short* __restrict__ zh,
    const unsigned short* __restrict__ wh, const unsigned short* __restrict__ wl,
    const float* __restrict__ c_in, const float* __restrict__ bf_,
    const float* __restrict__ bi_, const float* __restrict__ bc_,
    const float* __restrict__ bo_, float* __restrict__ out) {
  __shared__ unsigned short As[2 * 8192];    // 2 x 128 rows x 64 k = 32 KB
  __shared__ unsigned short Bhs[3 * 8192];   // 3 x 256 rows x 32 k = 48 KB
  __shared__ unsigned short Bls[3 * 8192];   // 48 KB
  const int t = threadIdx.x;
  const int lane = t & 63;
  const int wid = t >> 6;
  const int wr = wid >> 2;          // 0..1 M half (64 rows)
  const int wc = wid & 3;           // 0..3 N quarter (64 packed cols)
  const int l15 = lane & 15;
  const int l4 = lane >> 4;

  // XCD column-pinning: each XCD owns 2 col-panels (4 MB weights = L2-resident)
  const int bid = blockIdx.x;
  const int xcd = bid & 7;
  const int i = bid >> 3;           // 0..63
  const int bxc = (xcd << 1) | (i & 1);   // 0..15 col-block (256 packed cols)
  const int byr = i >> 1;                 // 0..31 row-block (128 rows)
  const int brow0 = byr << 7;
  const int pcol0 = bxc << 8;

  char* AsB = (char*)As;
  char* BhB = (char*)Bhs;
  char* BlB = (char*)Bls;

  // stage source offsets (LDS dest linear in t; source slot pre-swizzled)
  // A: [128 rows][8 slots of 16B], slot' = s ^ (row&7)
  // B: [256 rows][4 slots of 16B], slot' = s ^ ((row>>1)&3)
  int aoffA[2], boffB[2];
#pragma unroll
  for (int j = 0; j < 2; ++j) {
    int ra = (j << 6) + (t >> 3);
    aoffA[j] = (brow0 + ra) * KZ + (((t & 7) ^ (ra & 7)) << 3);
    int rb2 = (j << 7) + (t >> 2);
    boffB[j] = (pcol0 + rb2) * KZ + (((t & 3) ^ ((rb2 >> 1) & 3)) << 3);
  }

  auto STAGE_A = [&](int m) {                 // 2 loads; buffer parity m&1
    const int p = (m & 1) << 14;
    const int kb = m << 6;
#pragma unroll
    for (int j = 0; j < 2; ++j)
      gload_lds16(zh + aoffA[j] + kb, AsB + p + (j << 13) + (t << 4));
  };
  auto STAGE_B = [&](int s, int b) {          // 4 loads; buffer b in 0..2
    const int kb = s << 5;
    const int bb = b << 14;
#pragma unroll
    for (int j = 0; j < 2; ++j) {
      gload_lds16(wh + boffB[j] + kb, BhB + bb + (j << 13) + (t << 4));
      gload_lds16(wl + boffB[j] + kb, BlB + bb + (j << 13) + (t << 4));
    }
  };

  f32x4 acc[4][4];
#pragma unroll
  for (int mt = 0; mt < 4; ++mt)
#pragma unroll
    for (int nf = 0; nf < 4; ++nf) acc[mt][nf] = (f32x4){0.f, 0.f, 0.f, 0.f};

  // read constants
  const int rxA = l15 & 7;
  const int aRow = (wr << 13) + (l15 << 7);                    // + mt*2048 + sxA
  const int sxB = (l4 ^ ((l15 >> 1) & 3)) << 4;
  const int bRow = (wc << 12) + (l15 << 6) + sxB;              // + nf*1024

  short8 a[4], bh[4], bl[4];

  // prologue: A(0), B(0)->buf0, B(1)->buf1; leave B(1) in flight
  STAGE_A(0); STAGE_B(0, 0); STAGE_B(1, 1);
  VMC(4);
  BAR();

  int rb = 0, sb = 2;
  for (int s = 0; s < NSTEP; ++s) {
    const int h = s & 1;
    const int ap = ((s >> 1) & 1) << 14;
    const int sxA = (((h << 2) + l4) ^ rxA) << 4;
    const int bbase = rb << 14;

    // reads for this step (12)
#pragma unroll
    for (int mt = 0; mt < 4; ++mt)
      a[mt] = *reinterpret_cast<const short8*>(AsB + ap + aRow + (mt << 11) + sxA);
#pragma unroll
    for (int nf = 0; nf < 4; ++nf)
      bh[nf] = *reinterpret_cast<const short8*>(BhB + bbase + bRow + (nf << 10));
    SB();
#pragma unroll
    for (int nf = 0; nf < 4; ++nf)
      bl[nf] = *reinterpret_cast<const short8*>(BlB + bbase + bRow + (nf << 10));
    SB();

    // stages: B(s+2) into buf (s+2)%3; A(m+1) on even steps
    if (s < NSTEP - 2) {
      STAGE_B(s + 2, sb);
      if (h == 0) STAGE_A((s >> 1) + 1);
    }

    LGKM(4); SB();                 // a + bh ready (bl outstanding)
    PRIO1();
#pragma unroll
    for (int mt = 0; mt < 4; ++mt)
#pragma unroll
      for (int nf = 0; nf < 4; ++nf) acc[mt][nf] = MFMA(a[mt], bh[nf], acc[mt][nf]);
    PRIO0();
    LGKM(0); SB();                 // bl ready (all reads of this step complete)
    PRIO1();
#pragma unroll
    for (int mt = 0; mt < 4; ++mt)
#pragma unroll
      for (int nf = 0; nf < 4; ++nf) acc[mt][nf] = MFMA(a[mt], bl[nf], acc[mt][nf]);
    PRIO0();

    // counted drain: retire stages for step s+1 (issued during s-1); never 0 mid-loop
    if (s < NSTEP - 2) {
      if (h) { VMC(4); } else { VMC(6); }
    } else {
      VMC(0);
    }
    SB();
    BAR();
    rb = (rb == 2) ? 0 : rb + 1;
    sb = (sb == 2) ? 0 : sb + 1;
  }

  // ---- epilogue: lane holds all 4 gates (col-frags) for one column ----
  const int ng = (bxc << 6) + (wc << 4) + l15;
  const float vbf = bf_[ng], vbi = bi_[ng], vbc = bc_[ng], vbo = bo_[ng];
#pragma unroll
  for (int mt = 0; mt < 4; ++mt) {
#pragma unroll
    for (int r = 0; r < 4; ++r) {
      const int row = brow0 + (wr << 6) + (mt << 4) + (l4 << 2) + r;
      const float fp = acc[mt][0][r] + vbf;
      const float ip = acc[mt][1][r] + vbi;
      const float gp = acc[mt][2][r] + vbc;
      const float op = acc[mt][3][r] + vbo;
      const float co = c_in[(size_t)row * NG + ng];
      const float cnew = co * sigm(fp) + sigm(ip) * tanh_fast(gp);
      out[(size_t)row * NG + ng] = tanh_fast(cnew) * sigm(op);
    }
  }
}

extern "C" void kernel_launch(void* const* d_in, const int* in_sizes, int n_in,
                              void* d_out, int out_size, void* d_ws, size_t ws_size,
                              hipStream_t stream) {
  const float* x   = (const float*)d_in[0];
  const float* h   = (const float*)d_in[1];
  const float* c   = (const float*)d_in[2];
  const float* w_f = (const float*)d_in[3];
  const float* b_f = (const float*)d_in[4];
  const float* w_i = (const float*)d_in[5];
  const float* b_i = (const float*)d_in[6];
  const float* w_c = (const float*)d_in[7];
  const float* b_c = (const float*)d_in[8];
  const float* w_o = (const float*)d_in[9];
  const float* b_o = (const float*)d_in[10];
  float* out = (float*)d_out;

  unsigned short* zh = (unsigned short*)d_ws;                 // 16 MB
  unsigned short* wh = zh + (size_t)NB * KZ;                  // 16 MB
  unsigned short* wl = wh + (size_t)KZ * 4096;                // 16 MB

  zsplit_kernel<<<(NB * KZ / 4) / 256, 256, 0, stream>>>(x, h, zh);
  wsplit_kernel<<<dim3(KZ / 32, NG / 32, 4), 256, 0, stream>>>(w_f, w_i, w_c, w_o, wh, wl);
  lstm_gemm_kernel<<<512, 512, 0, stream>>>(zh, wh, wl, c,
                                            b_f, b_i, b_c, b_o, out);
}

// Round 13
// 134.117 us; speedup vs baseline: 1.2408x; 1.1304x over previous
//
#include <hip/hip_runtime.h>
#include <hip/hip_bf16.h>

typedef short short8 __attribute__((ext_vector_type(8)));
typedef float f32x4 __attribute__((ext_vector_type(4)));

#define NB 4096   // batch rows
#define KZ 2048   // concat K (IN + OUT)
#define NG 1024   // per-gate output cols
#define NH 64     // half-steps of K=32

__device__ __forceinline__ unsigned short f2bf(float f) {
  unsigned int u = __float_as_uint(f);
  u += 0x7FFFu + ((u >> 16) & 1u);   // RNE
  return (unsigned short)(u >> 16);
}
__device__ __forceinline__ float bf2f(unsigned short s) {
  return __uint_as_float(((unsigned int)s) << 16);
}
__device__ __forceinline__ void gload_lds16(const void* g, void* l) {
  __builtin_amdgcn_global_load_lds(
      (__attribute__((address_space(1))) void*)g,
      (__attribute__((address_space(3))) void*)l, 16, 0, 0);
}
__device__ __forceinline__ float sigm(float x) { return 1.f / (1.f + __expf(-x)); }
__device__ __forceinline__ float tanh_fast(float x) {
  float e = __expf(-2.f * fabsf(x));
  float r = (1.f - e) / (1.f + e);
  return copysignf(r, x);
}

// ---- concat([x,h]) -> bf16 zh [4096][2048] ----
__global__ void zsplit_kernel(const float* __restrict__ x, const float* __restrict__ h,
                              unsigned short* __restrict__ zh) {
  int idx = blockIdx.x * 256 + threadIdx.x;
  int e = idx << 2;
  int r = e >> 11;
  int k = e & (KZ - 1);
  const float* src = (k < 1024) ? (x + ((size_t)r << 10) + k)
                                : (h + ((size_t)r << 10) + (k - 1024));
  float4 v = *reinterpret_cast<const float4*>(src);
  float vf[4] = {v.x, v.y, v.z, v.w};
  unsigned short hh[4];
#pragma unroll
  for (int j = 0; j < 4; ++j) hh[j] = f2bf(vf[j]);
  uint2 H = make_uint2((unsigned)hh[0] | ((unsigned)hh[1] << 16),
                       (unsigned)hh[2] | ((unsigned)hh[3] << 16));
  *reinterpret_cast<uint2*>(zh + e) = H;
}

// ---- transpose + hi/lo split weights into gate-interleaved packed rows ----
// p = (n>>6)<<8 | ((n>>4)&3)<<6 | g<<4 | (n&15)   (each wave's 64 cols = 4 gates x 16)
__global__ void wsplit_kernel(const float* __restrict__ w0, const float* __restrict__ w1,
                              const float* __restrict__ w2, const float* __restrict__ w3,
                              unsigned short* __restrict__ wh, unsigned short* __restrict__ wl) {
  __shared__ float tile[32][33];
  int g = blockIdx.z;
  const float* w = (g == 0) ? w0 : (g == 1) ? w1 : (g == 2) ? w2 : w3;
  int k0 = blockIdx.x << 5;
  int n0 = blockIdx.y << 5;
  int t = threadIdx.x;
  int rk = t >> 3, q = t & 7;
  float4 v = *reinterpret_cast<const float4*>(w + (size_t)(k0 + rk) * NG + n0 + (q << 2));
  tile[rk][(q << 2) + 0] = v.x;
  tile[rk][(q << 2) + 1] = v.y;
  tile[rk][(q << 2) + 2] = v.z;
  tile[rk][(q << 2) + 3] = v.w;
  __syncthreads();
  int n = t >> 3, kq = t & 7;
  unsigned short hs[4], ls[4];
#pragma unroll
  for (int j = 0; j < 4; ++j) {
    float f = tile[(kq << 2) + j][n];
    unsigned short hi = f2bf(f);
    unsigned short lo = f2bf(f - bf2f(hi));
    hs[j] = hi; ls[j] = lo;
  }
  int nn = n0 + n;
  int p = ((nn >> 6) << 8) | (((nn >> 4) & 3) << 6) | (g << 4) | (nn & 15);
  size_t o = (size_t)p * KZ + k0 + (kq << 2);
  uint2 H = make_uint2((unsigned)hs[0] | ((unsigned)hs[1] << 16),
                       (unsigned)hs[2] | ((unsigned)hs[3] << 16));
  uint2 L = make_uint2((unsigned)ls[0] | ((unsigned)ls[1] << 16),
                       (unsigned)ls[2] | ((unsigned)ls[3] << 16));
  *reinterpret_cast<uint2*>(wh + o) = H;
  *reinterpret_cast<uint2*>(wl + o) = L;
}

#define MFMA(a, b, c) __builtin_amdgcn_mfma_f32_16x16x32_bf16((a), (b), (c), 0, 0, 0)
#define BAR() __builtin_amdgcn_s_barrier()
#define LGKM0() asm volatile("s_waitcnt lgkmcnt(0)" ::: "memory")
#define VMC(N) asm volatile("s_waitcnt vmcnt(" #N ")" ::: "memory")
#define SB() __builtin_amdgcn_sched_barrier(0)
#define PRIO1() __builtin_amdgcn_s_setprio(1)
#define PRIO0() __builtin_amdgcn_s_setprio(0)

// ---- 256x256 fused 4-gate GEMM + LSTM epilogue, read-ahead pipelined ----
// 8 waves (2M x 4N), wave = 128 rows x 64 packed cols, acc 8x4.
// A: [256r][64k] 8-slot-swizzled, dbuf per macro (K=64); staged on even halves.
// Bh/Bl: [256p][32k] 64B rows (bank-uniform), dbuf per half; staged 2 halves ahead.
// Per half: next half's B-frags read from LDS during this half's bl-MFMAs.
// Cross-wave safety: every staging load is retired by a vmcnt wait BEFORE the
// barrier that precedes its consuming reads (even-end VMC(4), odd-end VMC(0);
// all retired loads are >=1000 cyc old -> no fresh-load drains).
__global__ __launch_bounds__(512, 2) void lstm_gemm_kernel(
    const unsigned short* __restrict__ zh,
    const unsigned short* __restrict__ wh, const unsigned short* __restrict__ wl,
    const float* __restrict__ c_in, const float* __restrict__ bf_,
    const float* __restrict__ bi_, const float* __restrict__ bc_,
    const float* __restrict__ bo_, float* __restrict__ out) {
  __shared__ unsigned short As[2 * 16384];   // 64 KB
  __shared__ unsigned short Bhs[2 * 8192];   // 32 KB
  __shared__ unsigned short Bls[2 * 8192];   // 32 KB
  const int t = threadIdx.x;
  const int lane = t & 63;
  const int wid = t >> 6;
  const int wr = wid >> 2;
  const int wc = wid & 3;
  const int l15 = lane & 15;
  const int l4 = lane >> 4;

  // XCD column-pinning (weights L2-resident per XCD)
  const int bid = blockIdx.x;
  const int xcd = bid & 7;
  const int i = bid >> 3;                 // 0..31
  const int bxc = (xcd << 1) | (i & 1);   // 0..15 col-block
  const int byr = i >> 1;                 // 0..15 row-block
  const int brow0 = byr << 8;
  const int pcol0 = bxc << 8;

  char* AsB = (char*)As;
  char* BhB = (char*)Bhs;
  char* BlB = (char*)Bls;

  // A staging: [256r][8 slots 16B], source slot pre-swizzled s^(row&7)
  int aoffA[4];
#pragma unroll
  for (int j = 0; j < 4; ++j) {
    int ra = (j << 6) + (t >> 3);
    aoffA[j] = (brow0 + ra) * KZ + (((t & 7) ^ (ra & 7)) << 3);
  }
  // B staging: [256p][4 slots 16B], linear (bank-uniform at 64B stride)
  int boffB[2];
#pragma unroll
  for (int j = 0; j < 2; ++j)
    boffB[j] = (pcol0 + (j << 7) + (t >> 2)) * KZ + ((t & 3) << 3);

  auto ASTAGE = [&](int m) {   // A(m) -> buf parity m&1; 4 gloads
    const int kb = m << 6;
    const int p = (m & 1) << 15;
#pragma unroll
    for (int j = 0; j < 4; ++j)
      gload_lds16(zh + aoffA[j] + kb, AsB + p + (j << 13) + (t << 4));
  };
  auto BSTAGE = [&](int hh) {  // Bh(hh)+Bl(hh) -> bufs parity hh&1; 4 gloads
    const int kb = hh << 5;
    const int p = (hh & 1) << 14;
#pragma unroll
    for (int j = 0; j < 2; ++j)
      gload_lds16(wh + boffB[j] + kb, BhB + p + (j << 13) + (t << 4));
#pragma unroll
    for (int j = 0; j < 2; ++j)
      gload_lds16(wl + boffB[j] + kb, BlB + p + (j << 13) + (t << 4));
  };

  f32x4 acc[8][4];
#pragma unroll
  for (int m = 0; m < 8; ++m)
#pragma unroll
    for (int n = 0; n < 4; ++n) acc[m][n] = (f32x4){0.f, 0.f, 0.f, 0.f};

  // read constants
  const int rx = l15 & 7;
  const int aRow = (wr << 14) + (l15 << 7);          // + m*2048 + sx(q)
  const int sxA0 = (l4 ^ rx) << 4;
  const int sxA1 = ((4 + l4) ^ rx) << 4;
  const int bRow = (wc << 12) + (l15 << 6) + (l4 << 4);   // + nf*1024 + parity*16384

  short8 a[8], bhA[4], blA[4], bhB[4], blB[4];

  // prologue: A(0), B(0), B(1); retire A0+B0; BAR (cross-wave); read B(0) frags;
  // retire B(1); LGKM0; BAR.
  ASTAGE(0); BSTAGE(0); BSTAGE(1);
  VMC(4); SB();
  BAR();
#pragma unroll
  for (int nf = 0; nf < 4; ++nf) {
    bhA[nf] = *reinterpret_cast<const short8*>(BhB + bRow + (nf << 10));
    blA[nf] = *reinterpret_cast<const short8*>(BlB + bRow + (nf << 10));
  }
  VMC(0); SB();
  LGKM0(); SB();
  BAR();

// End-of-half wait: even half leaves A(hp+1) in flight (VMC 4); odd drains old.
#define HALF_BODY(H, HP, SX, APAR, CBH, CBL, NBH, NBL, EVMC)                    \
  {                                                                             \
    _Pragma("unroll")                                                           \
    for (int m = 0; m < 8; ++m)                                                 \
      a[m] = *reinterpret_cast<const short8*>(AsB + ((APAR) << 15) + aRow +     \
                                              (m << 11) + (SX));                \
    if ((H) + 2 < NH) BSTAGE((H) + 2);                                          \
    if ((((H) & 1) == 0) && ((HP) + 1 < 32)) ASTAGE((HP) + 1);                  \
    SB();                                                                       \
    PRIO1();                                                                    \
    _Pragma("unroll")                                                           \
    for (int m = 0; m < 8; ++m) {                                               \
      acc[m][0] = MFMA(a[m], CBH[0], acc[m][0]);                                \
      acc[m][1] = MFMA(a[m], CBH[1], acc[m][1]);                                \
      acc[m][2] = MFMA(a[m], CBH[2], acc[m][2]);                                \
      acc[m][3] = MFMA(a[m], CBH[3], acc[m][3]);                                \
    }                                                                           \
    PRIO0();                                                                    \
    SB();                                                                       \
    if ((H) + 1 < NH) {                                                         \
      const int np = (((H) + 1) & 1) << 14;                                     \
      _Pragma("unroll")                                                         \
      for (int nf = 0; nf < 4; ++nf) {                                          \
        NBH[nf] = *reinterpret_cast<const short8*>(BhB + np + bRow + (nf << 10));\
        NBL[nf] = *reinterpret_cast<const short8*>(BlB + np + bRow + (nf << 10));\
      }                                                                         \
    }                                                                           \
    SB();                                                                       \
    PRIO1();                                                                    \
    _Pragma("unroll")                                                           \
    for (int m = 0; m < 8; ++m) {                                               \
      acc[m][0] = MFMA(a[m], CBL[0], acc[m][0]);                                \
      acc[m][1] = MFMA(a[m], CBL[1], acc[m][1]);                                \
      acc[m][2] = MFMA(a[m], CBL[2], acc[m][2]);                                \
      acc[m][3] = MFMA(a[m], CBL[3], acc[m][3]);                                \
    }                                                                           \
    PRIO0();                                                                    \
    VMC(EVMC); SB();                                                            \
    LGKM0(); SB();                                                              \
    BAR();                                                                      \
  }

  for (int hp = 0; hp < 32; ++hp) {
    const int apar = hp & 1;
    HALF_BODY(2 * hp,     hp, sxA0, apar, bhA, blA, bhB, blB, 4);   // even half
    HALF_BODY(2 * hp + 1, hp, sxA1, apar, bhB, blB, bhA, blA, 0);   // odd half
  }

  // ---- epilogue: lane holds all 4 gates (col-frags) for one column ----
  const int ng = (bxc << 6) + (wc << 4) + l15;
  const float vbf = bf_[ng], vbi = bi_[ng], vbc = bc_[ng], vbo = bo_[ng];
#pragma unroll
  for (int m = 0; m < 8; ++m) {
#pragma unroll
    for (int r = 0; r < 4; ++r) {
      const int row = brow0 + (wr << 7) + (m << 4) + (l4 << 2) + r;
      const float fp = acc[m][0][r] + vbf;
      const float ip = acc[m][1][r] + vbi;
      const float gp = acc[m][2][r] + vbc;
      const float op = acc[m][3][r] + vbo;
      const float co = c_in[(size_t)row * NG + ng];
      const float cnew = co * sigm(fp) + sigm(ip) * tanh_fast(gp);
      out[(size_t)row * NG + ng] = tanh_fast(cnew) * sigm(op);
    }
  }
}

extern "C" void kernel_launch(void* const* d_in, const int* in_sizes, int n_in,
                              void* d_out, int out_size, void* d_ws, size_t ws_size,
                              hipStream_t stream) {
  const float* x   = (const float*)d_in[0];
  const float* h   = (const float*)d_in[1];
  const float* c   = (const float*)d_in[2];
  const float* w_f = (const float*)d_in[3];
  const float* b_f = (const float*)d_in[4];
  const float* w_i = (const float*)d_in[5];
  const float* b_i = (const float*)d_in[6];
  const float* w_c = (const float*)d_in[7];
  const float* b_c = (const float*)d_in[8];
  const float* w_o = (const float*)d_in[9];
  const float* b_o = (const float*)d_in[10];
  float* out = (float*)d_out;

  unsigned short* zh = (unsigned short*)d_ws;                 // 16 MB
  unsigned short* wh = zh + (size_t)NB * KZ;                  // 16 MB
  unsigned short* wl = wh + (size_t)KZ * 4096;                // 16 MB

  zsplit_kernel<<<(NB * KZ / 4) / 256, 256, 0, stream>>>(x, h, zh);
  wsplit_kernel<<<dim3(KZ / 32, NG / 32, 4), 256, 0, stream>>>(w_f, w_i, w_c, w_o, wh, wl);
  lstm_gemm_kernel<<<256, 512, 0, stream>>>(zh, wh, wl, c,
                                            b_f, b_i, b_c, b_o, out);
}